// Round 4
// baseline (288.212 us; speedup 1.0000x reference)
//
#include <hip/hip_runtime.h>
#include <hip/hip_bf16.h>
#include <cstddef>

#define T_LEN 50000

typedef __attribute__((ext_vector_type(8))) short bf16x8;
typedef __attribute__((ext_vector_type(4))) float f32x4;

__device__ __forceinline__ float sp_(float x){ return (x > 20.f) ? x : log1pf(expf(x)); }
__device__ __forceinline__ float gelu1(float x){ return 0.5f*x*(1.f + erff(x*0.7071067811865475f)); }

// ---------------- kernel 0: w_proj [160][100] fp32 -> wbf [160][128] bf16 (K zero-padded) ----
__global__ void k_cvtw(const float* __restrict__ wproj, __hip_bfloat16* __restrict__ wbf)
{
    int idx = blockIdx.x*256 + threadIdx.x;
    if (idx < 160*128) {
        int d = idx >> 7, i = idx & 127;
        float v = (i < 100) ? wproj[d*100 + i] : 0.f;
        wbf[idx] = __float2bfloat16(v);
    }
}

// ---------------- kernel 1: preprocessing chain -> xs bf16 [patch][128] + m_patch ----------
// UNCHANGED from round 2 (passed, 115 us) — kept byte-identical for attribution.
__global__ __launch_bounds__(256) void k_pre(
    const float* __restrict__ X, const float* __restrict__ Mq,
    const float* __restrict__ w_env, const float* __restrict__ w_bur,
    const float* __restrict__ syn, const float* __restrict__ wdw,
    const float* __restrict__ wpw,
    __hip_bfloat16* __restrict__ xs_out, float* __restrict__ mpatch)
{
    __shared__ float4 xb[1290];    // x tile, t in [t0-16, t0+1016), +1-per-4 padded
    __shared__ float4 s1b[1134];   // S1 tile, t in [t0-4, t0+1004), +1-per-8 padded
    __shared__ unsigned char maskb[1032];
    __shared__ float WnL[16];
    __shared__ float4 SmLUT[16];
    __shared__ __align__(16) __hip_bfloat16 abf[40*128];  // A-layout tile: [patch][i=m*25+k]

    const int tid  = threadIdx.x;
    const int b    = blockIdx.x / 50;
    const int tile = blockIdx.x % 50;
    const int t0   = tile * 1000;

    // ---- phase 1: load x = X*M (float4 over channels), build mask; zero abf K-pad ----
    const float4* X4 = (const float4*)X + (size_t)b * T_LEN;
    const float4* M4 = (const float4*)Mq + (size_t)b * T_LEN;
    #pragma unroll
    for (int jj = 0; jj < 5; ++jj) {
        int idx = tid + jj*256;
        if (idx < 1032) {
            int t = t0 - 16 + idx;
            float4 xv = make_float4(0.f,0.f,0.f,0.f);
            unsigned mk = 0u;
            if (t >= 0 && t < T_LEN) {
                float4 a = X4[t], m = M4[t];
                xv = make_float4(a.x*m.x, a.y*m.y, a.z*m.z, a.w*m.w);
                mk = (m.x>0.f?1u:0u) | (m.y>0.f?2u:0u) | (m.z>0.f?4u:0u) | (m.w>0.f?8u:0u);
            }
            xb[idx + (idx>>2)] = xv;
            maskb[idx] = (unsigned char)mk;
        }
    }
    for (int idx = tid; idx < 40*28; idx += 256) {   // zero i in [100,128)
        int p = idx / 28, i = 100 + idx % 28;
        abf[p*128 + i] = __float2bfloat16(0.f);
    }
    if (tid < 4) {
        float w0 = sp_(syn[tid*4+0]), w1 = sp_(syn[tid*4+1]);
        float w2 = sp_(syn[tid*4+2]), w3 = sp_(syn[tid*4+3]);
        float inv = 1.f / fmaxf(w0+w1+w2+w3, 1e-6f);
        WnL[tid*4+0]=w0*inv; WnL[tid*4+1]=w1*inv; WnL[tid*4+2]=w2*inv; WnL[tid*4+3]=w3*inv;
    }
    __syncthreads();
    if (tid < 16) {
        float sm[4];
        #pragma unroll
        for (int m=0;m<4;++m) {
            float a = 0.f;
            #pragma unroll
            for (int c=0;c<4;++c) if (tid & (1<<c)) a += WnL[m*4+c];
            sm[m] = fminf(a, 1.f);
        }
        SmLUT[tid] = make_float4(sm[0],sm[1],sm[2],sm[3]);
    }

    // ---- phase 2: env/burst/xm -> S1 for t in [t0-4, t0+1004) ----
    if (tid < 252) {
        float4 env[4], bur[4], xk[4];
        #pragma unroll
        for (int j=0;j<4;++j){ env[j]=make_float4(0,0,0,0); bur[j]=make_float4(0,0,0,0); }
        float4 xprev = make_float4(0,0,0,0);
        const int base  = 4*tid;
        const int gbase = t0 - 4 + 4*tid;
        #pragma unroll
        for (int s = -12; s <= 15; ++s) {
            int lt = base + (s+12);
            float4 xc = xb[lt + (lt>>2)];
            float4 ax = make_float4(fabsf(xc.x),fabsf(xc.y),fabsf(xc.z),fabsf(xc.w));
            if (s >= -4 && s <= 7) {
                int g = gbase + s;
                float4 dx;
                if (g <= 0 || g >= T_LEN) dx = make_float4(0,0,0,0);
                else dx = make_float4(xc.x-xprev.x, xc.y-xprev.y, xc.z-xprev.z, xc.w-xprev.w);
                float4 adx = make_float4(fabsf(dx.x),fabsf(dx.y),fabsf(dx.z),fabsf(dx.w));
                #pragma unroll
                for (int j=0;j<4;++j) {
                    int bk = s + 4 - j;
                    if (bk >= 0 && bk < 9) {
                        float b0=w_bur[bk], b1=w_bur[9+bk], b2=w_bur[18+bk], b3=w_bur[27+bk];
                        bur[j].x = fmaf(b0, adx.x, bur[j].x);
                        bur[j].y = fmaf(b1, adx.y, bur[j].y);
                        bur[j].z = fmaf(b2, adx.z, bur[j].z);
                        bur[j].w = fmaf(b3, adx.w, bur[j].w);
                    }
                }
            }
            #pragma unroll
            for (int j=0;j<4;++j) {
                int k = s + 12 - j;
                if (k >= 0 && k < 25) {
                    float e0=w_env[k], e1=w_env[25+k], e2=w_env[50+k], e3=w_env[75+k];
                    env[j].x = fmaf(e0, ax.x, env[j].x);
                    env[j].y = fmaf(e1, ax.y, env[j].y);
                    env[j].z = fmaf(e2, ax.z, env[j].z);
                    env[j].w = fmaf(e3, ax.w, env[j].w);
                }
            }
            if (s >= 0 && s <= 3) xk[s] = xc;
            xprev = xc;
        }
        #pragma unroll
        for (int j=0;j<4;++j) {
            int g = gbase + j;
            float4 xm = make_float4(
                0.9f*env[j].x + 0.6f*bur[j].x + 0.2f*xk[j].x,
                0.9f*env[j].y + 0.6f*bur[j].y + 0.2f*xk[j].y,
                0.9f*env[j].z + 0.6f*bur[j].z + 0.2f*xk[j].z,
                0.9f*env[j].w + 0.6f*bur[j].w + 0.2f*xk[j].w);
            float4 out = make_float4(0,0,0,0);
            if (g >= 0 && g < T_LEN) {
                out.x = WnL[0]*xm.x  + WnL[1]*xm.y  + WnL[2]*xm.z  + WnL[3]*xm.w;
                out.y = WnL[4]*xm.x  + WnL[5]*xm.y  + WnL[6]*xm.z  + WnL[7]*xm.w;
                out.z = WnL[8]*xm.x  + WnL[9]*xm.y  + WnL[10]*xm.z + WnL[11]*xm.w;
                out.w = WnL[12]*xm.x + WnL[13]*xm.y + WnL[14]*xm.z + WnL[15]*xm.w;
            }
            int ls = base + j;
            s1b[ls + (ls>>3)] = out;
        }
    }
    __syncthreads();

    // ---- phase 3: pre-dw + gelu + pw + gelu, * Sm -> abf (bf16, A-layout) ----
    if (tid < 250) {
        float4 s2a[4];
        #pragma unroll
        for (int j=0;j<4;++j) s2a[j]=make_float4(0,0,0,0);
        const int base = 4*tid;
        #pragma unroll
        for (int s = -4; s <= 7; ++s) {
            int ls = base + s + 4;
            float4 sc = s1b[ls + (ls>>3)];
            #pragma unroll
            for (int j=0;j<4;++j) {
                int k = s + 4 - j;
                if (k >= 0 && k < 9) {
                    float d0=wdw[k], d1=wdw[9+k], d2=wdw[18+k], d3=wdw[27+k];
                    s2a[j].x = fmaf(d0, sc.x, s2a[j].x);
                    s2a[j].y = fmaf(d1, sc.y, s2a[j].y);
                    s2a[j].z = fmaf(d2, sc.z, s2a[j].z);
                    s2a[j].w = fmaf(d3, sc.w, s2a[j].w);
                }
            }
        }
        #pragma unroll
        for (int j=0;j<4;++j) {
            int t = base + j;              // local t in [0,1000)
            float g0 = gelu1(s2a[j].x), g1 = gelu1(s2a[j].y);
            float g2 = gelu1(s2a[j].z), g3 = gelu1(s2a[j].w);
            float4 sm = SmLUT[maskb[t + 16]];
            int p = t / 25, k = t % 25;
            float smv[4] = {sm.x, sm.y, sm.z, sm.w};
            #pragma unroll
            for (int o=0;o<4;++o) {
                float v = wpw[o*4+0]*g0 + wpw[o*4+1]*g1 + wpw[o*4+2]*g2 + wpw[o*4+3]*g3;
                abf[p*128 + o*25 + k] = __float2bfloat16(gelu1(v) * smv[o]);
            }
        }
    }
    __syncthreads();

    // ---- phase 4: copy abf -> global (coalesced), m_patch from mask bits ----
    {
        const float4* src = (const float4*)abf;
        float4* dst = (float4*)(xs_out + (size_t)(b*2000 + tile*40)*128);
        #pragma unroll
        for (int it = 0; it < 3; ++it) {
            int idx = tid + it*256;
            if (idx < 640) dst[idx] = src[idx];
        }
    }
    // softplus > 0 strictly => all normalized W entries > 0 => sum_m Sm[t] > 0 <=> mask[t] != 0
    if (tid < 40) {
        int cnt = 0;
        #pragma unroll
        for (int k=0;k<25;++k) cnt += (maskb[16 + tid*25 + k] != 0) ? 1 : 0;
        mpatch[(size_t)b*2000 + tile*40 + tid] = (cnt >= 3) ? 1.f : 0.f;
    }
}

// ---------------- kernel 2: LDS-free MFMA patch projection + LayerNorm ------------------
// One wave = 16 patches, full K=128, all 160 d. No LDS, no barriers, fully independent waves.
// Fragments loaded straight from global: B = lane's own patch row (L2/L3), A = 40 KB wbf
// (L1/L2-hot, shared by all waves). Same fragment indices as the round-2 kernel (verified):
//   A lane(n,quad) row t*16+n, bytes kk*32+quad*8 ;  B lane(n,quad) patch p0w+n, same bytes.
// C/D: col = patch = lane&15, row = d = t*16 + quad*4 + r.
__global__ __launch_bounds__(256) void k_proj(
    const __hip_bfloat16* __restrict__ wbf, const __hip_bfloat16* __restrict__ xsg,
    const float* __restrict__ gamma, const float* __restrict__ beta,
    float* __restrict__ hout)
{
    const int tid  = threadIdx.x;
    const int wv   = tid >> 6, lane = tid & 63;
    const int n    = lane & 15, quad = lane >> 4;
    const int p0w  = (blockIdx.x*4 + wv) * 16;      // this wave's first patch
    const int prow = p0w + n;                        // this lane's patch (B column)

    // B fragments: 4 x 16B from this lane's patch row
    const __hip_bfloat16* ar = xsg + (size_t)prow*128 + quad*8;
    const bf16x8 pf0 = *(const bf16x8*)(ar);
    const bf16x8 pf1 = *(const bf16x8*)(ar + 32);
    const bf16x8 pf2 = *(const bf16x8*)(ar + 64);
    const bf16x8 pf3 = *(const bf16x8*)(ar + 96);

    f32x4 acc[10];
    #pragma unroll
    for (int t = 0; t < 10; ++t) acc[t] = (f32x4){0.f,0.f,0.f,0.f};

    const __hip_bfloat16* wr0 = wbf + (size_t)n*128 + quad*8;
    #pragma unroll
    for (int t = 0; t < 10; ++t) {
        const __hip_bfloat16* wr = wr0 + t*2048;     // row t*16+n
        const bf16x8 w0 = *(const bf16x8*)(wr);
        const bf16x8 w1 = *(const bf16x8*)(wr + 32);
        const bf16x8 w2 = *(const bf16x8*)(wr + 64);
        const bf16x8 w3 = *(const bf16x8*)(wr + 96);
        acc[t] = __builtin_amdgcn_mfma_f32_16x16x32_bf16(w0, pf0, acc[t], 0, 0, 0);
        acc[t] = __builtin_amdgcn_mfma_f32_16x16x32_bf16(w1, pf1, acc[t], 0, 0, 0);
        acc[t] = __builtin_amdgcn_mfma_f32_16x16x32_bf16(w2, pf2, acc[t], 0, 0, 0);
        acc[t] = __builtin_amdgcn_mfma_f32_16x16x32_bf16(w3, pf3, acc[t], 0, 0, 0);
    }

    // LayerNorm: lanes {n, n+16, n+32, n+48} hold patch prow's 4 d-quarters (40 each)
    float s = 0.f;
    #pragma unroll
    for (int t = 0; t < 10; ++t) {
        #pragma unroll
        for (int r = 0; r < 4; ++r) s += acc[t][r];
    }
    s += __shfl_xor(s, 16, 64); s += __shfl_xor(s, 32, 64);
    const float mu = s * (1.f/160.f);
    float q = 0.f;
    #pragma unroll
    for (int t = 0; t < 10; ++t) {
        #pragma unroll
        for (int r = 0; r < 4; ++r) { float dv = acc[t][r] - mu; q = fmaf(dv, dv, q); }
    }
    q += __shfl_xor(q, 16, 64); q += __shfl_xor(q, 32, 64);
    const float rs = rsqrtf(q * (1.f/160.f) + 1e-5f);

    float* hp = hout + (size_t)prow*160;
    #pragma unroll
    for (int t = 0; t < 10; ++t) {
        const float4 g  = *(const float4*)(gamma + t*16 + quad*4);
        const float4 be = *(const float4*)(beta  + t*16 + quad*4);
        float4 o;
        o.x = (acc[t][0] - mu)*rs*g.x + be.x;
        o.y = (acc[t][1] - mu)*rs*g.y + be.y;
        o.z = (acc[t][2] - mu)*rs*g.z + be.z;
        o.w = (acc[t][3] - mu)*rs*g.w + be.w;
        *(float4*)(hp + t*16 + quad*4) = o;
    }
}

extern "C" void kernel_launch(void* const* d_in, const int* in_sizes, int n_in,
                              void* d_out, int out_size, void* d_ws, size_t ws_size,
                              hipStream_t stream) {
    const float* X     = (const float*)d_in[0];
    const float* M     = (const float*)d_in[1];
    const float* w_env = (const float*)d_in[2];
    const float* w_bur = (const float*)d_in[3];
    const float* syn   = (const float*)d_in[4];
    const float* wdw   = (const float*)d_in[5];
    const float* wpw   = (const float*)d_in[6];
    const float* wproj = (const float*)d_in[7];
    const float* gam   = (const float*)d_in[8];
    const float* bet   = (const float*)d_in[9];

    float* h      = (float*)d_out;                       // (64,2000,160)
    float* mpatch = h + (size_t)64*2000*160;             // (64,2000)

    __hip_bfloat16* wbf = (__hip_bfloat16*)d_ws;                          // 40 KB
    __hip_bfloat16* xsb = (__hip_bfloat16*)((char*)d_ws + 65536);         // 128000*128*2 = 32.8 MB

    k_cvtw<<<80, 256, 0, stream>>>(wproj, wbf);
    k_pre<<<3200, 256, 0, stream>>>(X, M, w_env, w_bur, syn, wdw, wpw, xsb, mpatch);
    // 128000 patches / (4 waves * 16 patches) = 2000 blocks
    k_proj<<<2000, 256, 0, stream>>>(wbf, xsb, gam, bet, h);
}

// Round 5
// 267.194 us; speedup vs baseline: 1.0787x; 1.0787x over previous
//
#include <hip/hip_runtime.h>
#include <hip/hip_bf16.h>
#include <cstddef>

#define T_LEN 50000

typedef __attribute__((ext_vector_type(8))) short bf16x8;
typedef __attribute__((ext_vector_type(4))) float f32x4;

__device__ __forceinline__ float sp_(float x){ return (x > 20.f) ? x : log1pf(expf(x)); }
__device__ __forceinline__ float gelu1(float x){ return 0.5f*x*(1.f + erff(x*0.7071067811865475f)); }

// ---------------- kernel 0: w_proj [160][100] fp32 -> wbf [160][128] bf16 (K zero-padded) ----
__global__ void k_cvtw(const float* __restrict__ wproj, __hip_bfloat16* __restrict__ wbf)
{
    int idx = blockIdx.x*256 + threadIdx.x;
    if (idx < 160*128) {
        int d = idx >> 7, i = idx & 127;
        float v = (i < 100) ? wproj[d*100 + i] : 0.f;
        wbf[idx] = __float2bfloat16(v);
    }
}

// ---------------- fused kernel: preprocessing chain + MFMA projection + LayerNorm ----------
// block: 256 threads, tile = 1000 t (40 patches). grid = 64*50.
// Phases 1-3 byte-identical math to the round-2-verified k_pre. Then, in-block:
// projection of the 40-patch abf tile (padded to 48 rows) against W (staged to VGPRs from
// global once per block), cross-wave two-pass LayerNorm, float4 stores of h.
// LDS: xb 20640 + s1b 18144 + abf 13056 + maskb 1032 + WnL 64 + SmLUT 256 + part 1536
//    = 54728 B -> 2 blocks/CU.
__global__ __launch_bounds__(256, 2) void k_fused(
    const float* __restrict__ X, const float* __restrict__ Mq,
    const float* __restrict__ w_env, const float* __restrict__ w_bur,
    const float* __restrict__ syn, const float* __restrict__ wdw,
    const float* __restrict__ wpw, const __hip_bfloat16* __restrict__ wbf,
    const float* __restrict__ gamma, const float* __restrict__ beta,
    float* __restrict__ hout, float* __restrict__ mpatch)
{
    __shared__ float4 xb[1290];    // x tile, t in [t0-16, t0+1016), +1-per-4 padded
    __shared__ float4 s1b[1134];   // S1 tile, t in [t0-4, t0+1004), +1-per-8 padded
    __shared__ unsigned char maskb[1032];
    __shared__ float WnL[16];
    __shared__ float4 SmLUT[16];
    __shared__ __align__(16) __hip_bfloat16 abf[48*136];  // [patch(+pad)][K pad 136]
    __shared__ float partS[4][3][16];   // per-wave LN sum partials
    __shared__ float partQ[4][3][16];   // per-wave LN sq-dev partials

    const int tid  = threadIdx.x;
    const int b    = blockIdx.x / 50;
    const int tile = blockIdx.x % 50;
    const int t0   = tile * 1000;

    // ---- phase 1: load x = X*M (float4 over channels), build mask; zero abf pads ----
    const float4* X4 = (const float4*)X + (size_t)b * T_LEN;
    const float4* M4 = (const float4*)Mq + (size_t)b * T_LEN;
    #pragma unroll
    for (int jj = 0; jj < 5; ++jj) {
        int idx = tid + jj*256;
        if (idx < 1032) {
            int t = t0 - 16 + idx;
            float4 xv = make_float4(0.f,0.f,0.f,0.f);
            unsigned mk = 0u;
            if (t >= 0 && t < T_LEN) {
                float4 a = X4[t], m = M4[t];
                xv = make_float4(a.x*m.x, a.y*m.y, a.z*m.z, a.w*m.w);
                mk = (m.x>0.f?1u:0u) | (m.y>0.f?2u:0u) | (m.z>0.f?4u:0u) | (m.w>0.f?8u:0u);
            }
            xb[idx + (idx>>2)] = xv;
            maskb[idx] = (unsigned char)mk;
        }
    }
    // zero: rows 0-39 K-pad i in [100,128); rows 40-47 (patch pad) i in [0,128)
    for (int idx = tid; idx < 1120 + 1024; idx += 256) {
        int p, i;
        if (idx < 1120) { p = idx / 28; i = 100 + idx % 28; }
        else { int j = idx - 1120; p = 40 + (j >> 7); i = j & 127; }
        abf[p*136 + i] = __float2bfloat16(0.f);
    }
    if (tid < 4) {
        float w0 = sp_(syn[tid*4+0]), w1 = sp_(syn[tid*4+1]);
        float w2 = sp_(syn[tid*4+2]), w3 = sp_(syn[tid*4+3]);
        float inv = 1.f / fmaxf(w0+w1+w2+w3, 1e-6f);
        WnL[tid*4+0]=w0*inv; WnL[tid*4+1]=w1*inv; WnL[tid*4+2]=w2*inv; WnL[tid*4+3]=w3*inv;
    }
    __syncthreads();
    if (tid < 16) {
        float sm[4];
        #pragma unroll
        for (int m=0;m<4;++m) {
            float a = 0.f;
            #pragma unroll
            for (int c=0;c<4;++c) if (tid & (1<<c)) a += WnL[m*4+c];
            sm[m] = fminf(a, 1.f);
        }
        SmLUT[tid] = make_float4(sm[0],sm[1],sm[2],sm[3]);
    }

    // ---- phase 2: env/burst/xm -> S1 for t in [t0-4, t0+1004) ----
    if (tid < 252) {
        float4 env[4], bur[4], xk[4];
        #pragma unroll
        for (int j=0;j<4;++j){ env[j]=make_float4(0,0,0,0); bur[j]=make_float4(0,0,0,0); }
        float4 xprev = make_float4(0,0,0,0);
        const int base  = 4*tid;
        const int gbase = t0 - 4 + 4*tid;
        #pragma unroll
        for (int s = -12; s <= 15; ++s) {
            int lt = base + (s+12);
            float4 xc = xb[lt + (lt>>2)];
            float4 ax = make_float4(fabsf(xc.x),fabsf(xc.y),fabsf(xc.z),fabsf(xc.w));
            if (s >= -4 && s <= 7) {
                int g = gbase + s;
                float4 dx;
                if (g <= 0 || g >= T_LEN) dx = make_float4(0,0,0,0);
                else dx = make_float4(xc.x-xprev.x, xc.y-xprev.y, xc.z-xprev.z, xc.w-xprev.w);
                float4 adx = make_float4(fabsf(dx.x),fabsf(dx.y),fabsf(dx.z),fabsf(dx.w));
                #pragma unroll
                for (int j=0;j<4;++j) {
                    int bk = s + 4 - j;
                    if (bk >= 0 && bk < 9) {
                        float b0=w_bur[bk], b1=w_bur[9+bk], b2=w_bur[18+bk], b3=w_bur[27+bk];
                        bur[j].x = fmaf(b0, adx.x, bur[j].x);
                        bur[j].y = fmaf(b1, adx.y, bur[j].y);
                        bur[j].z = fmaf(b2, adx.z, bur[j].z);
                        bur[j].w = fmaf(b3, adx.w, bur[j].w);
                    }
                }
            }
            #pragma unroll
            for (int j=0;j<4;++j) {
                int k = s + 12 - j;
                if (k >= 0 && k < 25) {
                    float e0=w_env[k], e1=w_env[25+k], e2=w_env[50+k], e3=w_env[75+k];
                    env[j].x = fmaf(e0, ax.x, env[j].x);
                    env[j].y = fmaf(e1, ax.y, env[j].y);
                    env[j].z = fmaf(e2, ax.z, env[j].z);
                    env[j].w = fmaf(e3, ax.w, env[j].w);
                }
            }
            if (s >= 0 && s <= 3) xk[s] = xc;
            xprev = xc;
        }
        #pragma unroll
        for (int j=0;j<4;++j) {
            int g = gbase + j;
            float4 xm = make_float4(
                0.9f*env[j].x + 0.6f*bur[j].x + 0.2f*xk[j].x,
                0.9f*env[j].y + 0.6f*bur[j].y + 0.2f*xk[j].y,
                0.9f*env[j].z + 0.6f*bur[j].z + 0.2f*xk[j].z,
                0.9f*env[j].w + 0.6f*bur[j].w + 0.2f*xk[j].w);
            float4 out = make_float4(0,0,0,0);
            if (g >= 0 && g < T_LEN) {
                out.x = WnL[0]*xm.x  + WnL[1]*xm.y  + WnL[2]*xm.z  + WnL[3]*xm.w;
                out.y = WnL[4]*xm.x  + WnL[5]*xm.y  + WnL[6]*xm.z  + WnL[7]*xm.w;
                out.z = WnL[8]*xm.x  + WnL[9]*xm.y  + WnL[10]*xm.z + WnL[11]*xm.w;
                out.w = WnL[12]*xm.x + WnL[13]*xm.y + WnL[14]*xm.z + WnL[15]*xm.w;
            }
            int ls = base + j;
            s1b[ls + (ls>>3)] = out;
        }
    }
    __syncthreads();

    // ---- phase 3: pre-dw + gelu + pw + gelu, * Sm -> abf (bf16, stride 136) ----
    if (tid < 250) {
        float4 s2a[4];
        #pragma unroll
        for (int j=0;j<4;++j) s2a[j]=make_float4(0,0,0,0);
        const int base = 4*tid;
        #pragma unroll
        for (int s = -4; s <= 7; ++s) {
            int ls = base + s + 4;
            float4 sc = s1b[ls + (ls>>3)];
            #pragma unroll
            for (int j=0;j<4;++j) {
                int k = s + 4 - j;
                if (k >= 0 && k < 9) {
                    float d0=wdw[k], d1=wdw[9+k], d2=wdw[18+k], d3=wdw[27+k];
                    s2a[j].x = fmaf(d0, sc.x, s2a[j].x);
                    s2a[j].y = fmaf(d1, sc.y, s2a[j].y);
                    s2a[j].z = fmaf(d2, sc.z, s2a[j].z);
                    s2a[j].w = fmaf(d3, sc.w, s2a[j].w);
                }
            }
        }
        #pragma unroll
        for (int j=0;j<4;++j) {
            int t = base + j;              // local t in [0,1000)
            float g0 = gelu1(s2a[j].x), g1 = gelu1(s2a[j].y);
            float g2 = gelu1(s2a[j].z), g3 = gelu1(s2a[j].w);
            float4 sm = SmLUT[maskb[t + 16]];
            int p = t / 25, k = t % 25;
            float smv[4] = {sm.x, sm.y, sm.z, sm.w};
            #pragma unroll
            for (int o=0;o<4;++o) {
                float v = wpw[o*4+0]*g0 + wpw[o*4+1]*g1 + wpw[o*4+2]*g2 + wpw[o*4+3]*g3;
                abf[p*136 + o*25 + k] = __float2bfloat16(gelu1(v) * smv[o]);
            }
        }
    }
    __syncthreads();

    // ---- phase 4: in-block MFMA projection + two-pass LayerNorm + store h ----
    // Waves own d-tiles: w0:{0,1,2} w1:{3,4,5} w2:{6,7} w3:{8,9}. Patch-tiles pt=0,1,2
    // cover rows 0-15,16-31,32-47 (40-47 = zeroed pad, never stored).
    // C/D layout (operand-swap, verified r2/r4): row = d = dt*16+quad*4+r, col = patch = pt*16+n.
    {
        const int lane = tid & 63;
        const int wv   = tid >> 6;
        const int n    = lane & 15, quad = lane >> 4;
        const int ndt  = (wv < 2) ? 3 : 2;
        const int dt0  = (wv < 2) ? wv*3 : 6 + (wv-2)*2;

        // W fragments from global, once per block (12 KB max per wave, L2-hot)
        bf16x8 wf[3][4];
        #pragma unroll
        for (int i = 0; i < 3; ++i) {
            if (i < ndt) {
                const __hip_bfloat16* wr = wbf + (size_t)((dt0+i)*16 + n)*128 + quad*8;
                #pragma unroll
                for (int kk = 0; kk < 4; ++kk) wf[i][kk] = *(const bf16x8*)(wr + kk*32);
            }
        }

        f32x4 acc[3][3];
        #pragma unroll
        for (int i=0;i<3;++i) {
            #pragma unroll
            for (int pt=0;pt<3;++pt) acc[i][pt] = (f32x4){0.f,0.f,0.f,0.f};
        }
        #pragma unroll
        for (int kk = 0; kk < 4; ++kk) {
            const bf16x8 pf0 = *(const bf16x8*)(abf + ( 0+n)*136 + kk*32 + quad*8);
            const bf16x8 pf1 = *(const bf16x8*)(abf + (16+n)*136 + kk*32 + quad*8);
            const bf16x8 pf2 = *(const bf16x8*)(abf + (32+n)*136 + kk*32 + quad*8);
            #pragma unroll
            for (int i = 0; i < 3; ++i) {
                if (i < ndt) {
                    acc[i][0] = __builtin_amdgcn_mfma_f32_16x16x32_bf16(wf[i][kk], pf0, acc[i][0], 0, 0, 0);
                    acc[i][1] = __builtin_amdgcn_mfma_f32_16x16x32_bf16(wf[i][kk], pf1, acc[i][1], 0, 0, 0);
                    acc[i][2] = __builtin_amdgcn_mfma_f32_16x16x32_bf16(wf[i][kk], pf2, acc[i][2], 0, 0, 0);
                }
            }
        }

        // LN pass 1: per-patch sums (this wave's d-rows), cross-wave via LDS
        float mu[3];
        #pragma unroll
        for (int pt = 0; pt < 3; ++pt) {
            float s = 0.f;
            #pragma unroll
            for (int i = 0; i < 3; ++i) {
                if (i < ndt) {
                    #pragma unroll
                    for (int r = 0; r < 4; ++r) s += acc[i][pt][r];
                }
            }
            s += __shfl_xor(s, 16, 64); s += __shfl_xor(s, 32, 64);
            if (quad == 0) partS[wv][pt][n] = s;
        }
        __syncthreads();
        #pragma unroll
        for (int pt = 0; pt < 3; ++pt)
            mu[pt] = (partS[0][pt][n] + partS[1][pt][n] + partS[2][pt][n] + partS[3][pt][n]) * (1.f/160.f);

        // LN pass 2: per-patch sum of squared deviations
        float rs[3];
        #pragma unroll
        for (int pt = 0; pt < 3; ++pt) {
            float q = 0.f;
            #pragma unroll
            for (int i = 0; i < 3; ++i) {
                if (i < ndt) {
                    #pragma unroll
                    for (int r = 0; r < 4; ++r) { float dv = acc[i][pt][r] - mu[pt]; q = fmaf(dv, dv, q); }
                }
            }
            q += __shfl_xor(q, 16, 64); q += __shfl_xor(q, 32, 64);
            if (quad == 0) partQ[wv][pt][n] = q;
        }
        __syncthreads();
        #pragma unroll
        for (int pt = 0; pt < 3; ++pt) {
            float q = partQ[0][pt][n] + partQ[1][pt][n] + partQ[2][pt][n] + partQ[3][pt][n];
            rs[pt] = rsqrtf(q * (1.f/160.f) + 1e-5f);
        }

        // store h (skip pad patches 40-47)
        #pragma unroll
        for (int pt = 0; pt < 3; ++pt) {
            if (pt == 2 && n >= 8) continue;
            float* hp = hout + (size_t)(b*2000 + tile*40 + pt*16 + n)*160;
            #pragma unroll
            for (int i = 0; i < 3; ++i) {
                if (i < ndt) {
                    const int d0 = (dt0+i)*16 + quad*4;
                    const float4 g  = *(const float4*)(gamma + d0);
                    const float4 be = *(const float4*)(beta  + d0);
                    float4 o;
                    o.x = (acc[i][pt][0] - mu[pt])*rs[pt]*g.x + be.x;
                    o.y = (acc[i][pt][1] - mu[pt])*rs[pt]*g.y + be.y;
                    o.z = (acc[i][pt][2] - mu[pt])*rs[pt]*g.z + be.z;
                    o.w = (acc[i][pt][3] - mu[pt])*rs[pt]*g.w + be.w;
                    *(float4*)(hp + d0) = o;
                }
            }
        }
    }

    // ---- m_patch from mask bits (softplus>0 => sum_m Sm>0 <=> mask != 0) ----
    if (tid < 40) {
        int cnt = 0;
        #pragma unroll
        for (int k=0;k<25;++k) cnt += (maskb[16 + tid*25 + k] != 0) ? 1 : 0;
        mpatch[(size_t)b*2000 + tile*40 + tid] = (cnt >= 3) ? 1.f : 0.f;
    }
}

extern "C" void kernel_launch(void* const* d_in, const int* in_sizes, int n_in,
                              void* d_out, int out_size, void* d_ws, size_t ws_size,
                              hipStream_t stream) {
    const float* X     = (const float*)d_in[0];
    const float* M     = (const float*)d_in[1];
    const float* w_env = (const float*)d_in[2];
    const float* w_bur = (const float*)d_in[3];
    const float* syn   = (const float*)d_in[4];
    const float* wdw   = (const float*)d_in[5];
    const float* wpw   = (const float*)d_in[6];
    const float* wproj = (const float*)d_in[7];
    const float* gam   = (const float*)d_in[8];
    const float* bet   = (const float*)d_in[9];

    float* h      = (float*)d_out;                       // (64,2000,160)
    float* mpatch = h + (size_t)64*2000*160;             // (64,2000)

    __hip_bfloat16* wbf = (__hip_bfloat16*)d_ws;         // 40 KB

    k_cvtw<<<80, 256, 0, stream>>>(wproj, wbf);
    k_fused<<<3200, 256, 0, stream>>>(X, M, w_env, w_bur, syn, wdw, wpw, wbf, gam, bet, h, mpatch);
}